// Round 1
// baseline (960.005 us; speedup 1.0000x reference)
//
#include <hip/hip_runtime.h>

typedef float f4 __attribute__((ext_vector_type(4)));

struct F3 { float x, y, z; };

__device__ __forceinline__ F3 ldf3(const float* __restrict__ p) {
    F3 r;
    __builtin_memcpy(&r, p, sizeof(F3));   // 12B, align 4 -> dwordx3
    return r;
}
__device__ __forceinline__ F3 sub3(F3 a, F3 b) { F3 r{a.x - b.x, a.y - b.y, a.z - b.z}; return r; }
__device__ __forceinline__ float nrm3(F3 v) { return sqrtf(v.x * v.x + v.y * v.y + v.z * v.z); }

__device__ __forceinline__ void stnt4(f4* __restrict__ p, float a, float b, float c, float d) {
    f4 v; v.x = a; v.y = b; v.z = c; v.w = d;
    __builtin_nontemporal_store(v, p);
}

// Store fwd rows for cells (c0, c0+1) of one region (64B contiguous) + the
// reversed region (negated rels, same norms), also 64B contiguous.
__device__ __forceinline__ void store_pair(f4* __restrict__ ef, size_t fb, size_t rb,
                                           F3 rw0, float nw0, F3 rm0, float nm0,
                                           F3 rw1, float nw1, F3 rm1, float nm1) {
    stnt4(ef + fb + 0,  rw0.x,  rw0.y,  rw0.z, nw0);
    stnt4(ef + fb + 1,  rm0.x,  rm0.y,  rm0.z, nm0);
    stnt4(ef + fb + 2,  rw1.x,  rw1.y,  rw1.z, nw1);
    stnt4(ef + fb + 3,  rm1.x,  rm1.y,  rm1.z, nm1);
    stnt4(ef + rb + 0, -rw0.x, -rw0.y, -rw0.z, nw0);
    stnt4(ef + rb + 1, -rm0.x, -rm0.y, -rm0.z, nm0);
    stnt4(ef + rb + 2, -rw1.x, -rw1.y, -rw1.z, nw1);
    stnt4(ef + rb + 3, -rm1.x, -rm1.y, -rm1.z, nm1);
}

__device__ __forceinline__ void node_rows(f4* __restrict__ dst, float vx, float vy, float vz, int t) {
    stnt4(dst + 0, vx, vy, vz, t == 0 ? 1.f : 0.f);
    stnt4(dst + 1, t == 1 ? 1.f : 0.f, t == 2 ? 1.f : 0.f, t == 3 ? 1.f : 0.f, t == 4 ? 1.f : 0.f);
    stnt4(dst + 2, t == 5 ? 1.f : 0.f, t == 6 ? 1.f : 0.f, t == 7 ? 1.f : 0.f, t == 8 ? 1.f : 0.f);
}

// Scalar fallback for a single (tail) cell.
__device__ __forceinline__ void edge_one(const float* __restrict__ world,
                                         const float* __restrict__ mesh,
                                         const int* __restrict__ cells,
                                         f4* __restrict__ ef, size_t NC, size_t c) {
    const int* cb = cells + 3 * c;
    int ia = cb[0], ib = cb[1], ic = cb[2];
    F3 wa = ldf3(world + 3 * (size_t)ia), wb = ldf3(world + 3 * (size_t)ib), wc = ldf3(world + 3 * (size_t)ic);
    F3 ma = ldf3(mesh  + 3 * (size_t)ia), mb = ldf3(mesh  + 3 * (size_t)ib), mc = ldf3(mesh  + 3 * (size_t)ic);
    {   // a->b at c ; rev at c+3NC
        F3 rw = sub3(wa, wb), rm = sub3(ma, mb);
        float nw = nrm3(rw), nm = nrm3(rm);
        size_t e = c, er = c + 3 * NC;
        stnt4(ef + 2 * e + 0,  rw.x,  rw.y,  rw.z, nw); stnt4(ef + 2 * e + 1,  rm.x,  rm.y,  rm.z, nm);
        stnt4(ef + 2 * er + 0, -rw.x, -rw.y, -rw.z, nw); stnt4(ef + 2 * er + 1, -rm.x, -rm.y, -rm.z, nm);
    }
    {   // b->c at c+NC ; rev at c+4NC
        F3 rw = sub3(wb, wc), rm = sub3(mb, mc);
        float nw = nrm3(rw), nm = nrm3(rm);
        size_t e = c + NC, er = c + 4 * NC;
        stnt4(ef + 2 * e + 0,  rw.x,  rw.y,  rw.z, nw); stnt4(ef + 2 * e + 1,  rm.x,  rm.y,  rm.z, nm);
        stnt4(ef + 2 * er + 0, -rw.x, -rw.y, -rw.z, nw); stnt4(ef + 2 * er + 1, -rm.x, -rm.y, -rm.z, nm);
    }
    {   // c->a at c+2NC ; rev at c+5NC
        F3 rw = sub3(wc, wa), rm = sub3(mc, ma);
        float nw = nrm3(rw), nm = nrm3(rm);
        size_t e = c + 2 * NC, er = c + 5 * NC;
        stnt4(ef + 2 * e + 0,  rw.x,  rw.y,  rw.z, nw); stnt4(ef + 2 * e + 1,  rm.x,  rm.y,  rm.z, nm);
        stnt4(ef + 2 * er + 0, -rw.x, -rw.y, -rw.z, nw); stnt4(ef + 2 * er + 1, -rm.x, -rm.y, -rm.z, nm);
    }
}

__global__ void __launch_bounds__(256) fused(const float* __restrict__ world,
                                             const float* __restrict__ prev,
                                             const float* __restrict__ mesh,
                                             const int* __restrict__ ntype,
                                             const int* __restrict__ cells,
                                             f4* __restrict__ nf,
                                             f4* __restrict__ ef,
                                             int n_nodes, int n_cells, int edge_blocks) {
    if ((int)blockIdx.x < edge_blocks) {
        // ---------------- edge path: 2 cells per thread ----------------
        int p = blockIdx.x * 256 + threadIdx.x;
        int npairs = n_cells >> 1;
        size_t NC = (size_t)n_cells;
        if (p < npairs) {
            const int2* cb = (const int2*)(cells + 6 * (size_t)p);   // 24B-aligned mod 8
            int2 q0 = cb[0], q1 = cb[1], q2 = cb[2];
            int ia0 = q0.x, ib0 = q0.y, ic0 = q1.x;
            int ia1 = q1.y, ib1 = q2.x, ic1 = q2.y;

            F3 wa0 = ldf3(world + 3 * (size_t)ia0);
            F3 wb0 = ldf3(world + 3 * (size_t)ib0);
            F3 wc0 = ldf3(world + 3 * (size_t)ic0);
            F3 wa1 = ldf3(world + 3 * (size_t)ia1);
            F3 wb1 = ldf3(world + 3 * (size_t)ib1);
            F3 wc1 = ldf3(world + 3 * (size_t)ic1);
            F3 ma0 = ldf3(mesh + 3 * (size_t)ia0);
            F3 mb0 = ldf3(mesh + 3 * (size_t)ib0);
            F3 mc0 = ldf3(mesh + 3 * (size_t)ic0);
            F3 ma1 = ldf3(mesh + 3 * (size_t)ia1);
            F3 mb1 = ldf3(mesh + 3 * (size_t)ib1);
            F3 mc1 = ldf3(mesh + 3 * (size_t)ic1);

            size_t c0 = 2 * (size_t)p;
            {   // region 0: a-b ; reverse region 3
                F3 rw0 = sub3(wa0, wb0), rm0 = sub3(ma0, mb0);
                F3 rw1 = sub3(wa1, wb1), rm1 = sub3(ma1, mb1);
                store_pair(ef, 2 * (0 * NC + c0), 2 * (3 * NC + c0),
                           rw0, nrm3(rw0), rm0, nrm3(rm0), rw1, nrm3(rw1), rm1, nrm3(rm1));
            }
            {   // region 1: b-c ; reverse region 4
                F3 rw0 = sub3(wb0, wc0), rm0 = sub3(mb0, mc0);
                F3 rw1 = sub3(wb1, wc1), rm1 = sub3(mb1, mc1);
                store_pair(ef, 2 * (1 * NC + c0), 2 * (4 * NC + c0),
                           rw0, nrm3(rw0), rm0, nrm3(rm0), rw1, nrm3(rw1), rm1, nrm3(rm1));
            }
            {   // region 2: c-a ; reverse region 5
                F3 rw0 = sub3(wc0, wa0), rm0 = sub3(mc0, ma0);
                F3 rw1 = sub3(wc1, wa1), rm1 = sub3(mc1, ma1);
                store_pair(ef, 2 * (2 * NC + c0), 2 * (5 * NC + c0),
                           rw0, nrm3(rw0), rm0, nrm3(rm0), rw1, nrm3(rw1), rm1, nrm3(rm1));
            }
        } else if ((n_cells & 1) && p == npairs) {
            edge_one(world, mesh, cells, ef, NC, (size_t)n_cells - 1);
        }
    } else {
        // ---------------- node path: 4 nodes per thread ----------------
        int t = (blockIdx.x - edge_blocks) * 256 + threadIdx.x;
        int n4 = n_nodes >> 2;
        if (t < n4) {
            const f4* w4 = (const f4*)world + 3 * (size_t)t;
            const f4* p4 = (const f4*)prev  + 3 * (size_t)t;
            f4 wv0 = w4[0], wv1 = w4[1], wv2 = w4[2];
            f4 pv0 = p4[0], pv1 = p4[1], pv2 = p4[2];
            int4 tt = *((const int4*)ntype + t);
            f4* dst = nf + 12 * (size_t)t;
            node_rows(dst + 0, wv0.x - pv0.x, wv0.y - pv0.y, wv0.z - pv0.z, tt.x);
            node_rows(dst + 3, wv0.w - pv0.w, wv1.x - pv1.x, wv1.y - pv1.y, tt.y);
            node_rows(dst + 6, wv1.z - pv1.z, wv1.w - pv1.w, wv2.x - pv2.x, tt.z);
            node_rows(dst + 9, wv2.y - pv2.y, wv2.z - pv2.z, wv2.w - pv2.w, tt.w);
        } else {
            int k = t - n4;
            int n = (n4 << 2) + k;
            if (n < n_nodes) {
                size_t b = 3 * (size_t)n;
                float vx = world[b + 0] - prev[b + 0];
                float vy = world[b + 1] - prev[b + 1];
                float vz = world[b + 2] - prev[b + 2];
                node_rows(nf + 3 * (size_t)n, vx, vy, vz, ntype[n]);
            }
        }
    }
}

extern "C" void kernel_launch(void* const* d_in, const int* in_sizes, int n_in,
                              void* d_out, int out_size, void* d_ws, size_t ws_size,
                              hipStream_t stream) {
    const float* world = (const float*)d_in[0];
    const float* prev  = (const float*)d_in[1];
    const float* mesh  = (const float*)d_in[2];
    const int* ntype   = (const int*)d_in[3];
    const int* cells   = (const int*)d_in[4];
    int n_nodes = in_sizes[0] / 3;   // 1,000,000
    int n_cells = in_sizes[4] / 3;   // 2,000,000

    float* out = (float*)d_out;
    f4* nf = (f4*)out;                                   // node features: n_nodes x 12 f32
    f4* ef = (f4*)(out + (size_t)n_nodes * 12);          // edge features: 6*n_cells x 8 f32

    int npairs = n_cells >> 1;
    int edge_threads = npairs + (n_cells & 1);
    int edge_blocks = (edge_threads + 255) / 256;
    int n4 = n_nodes >> 2;
    int node_threads = n4 + (n_nodes - (n4 << 2));
    int node_blocks = (node_threads + 255) / 256;

    fused<<<dim3(edge_blocks + node_blocks), dim3(256), 0, stream>>>(
        world, prev, mesh, ntype, cells, nf, ef, n_nodes, n_cells, edge_blocks);
}

// Round 2
// 546.391 us; speedup vs baseline: 1.7570x; 1.7570x over previous
//
#include <hip/hip_runtime.h>

typedef float f4 __attribute__((ext_vector_type(4)));

struct F3 { float x, y, z; };
struct I3 { int a, b, c; };

__device__ __forceinline__ F3 ldf3(const float* __restrict__ p) {
    F3 r;
    __builtin_memcpy(&r, p, sizeof(F3));   // 12B, align 4 -> global_load_dwordx3
    return r;
}
__device__ __forceinline__ F3 sub3(F3 a, F3 b) { F3 r{a.x - b.x, a.y - b.y, a.z - b.z}; return r; }
__device__ __forceinline__ float nrm3(F3 v) { return sqrtf(v.x * v.x + v.y * v.y + v.z * v.z); }

// One edge pair (forward + reversed). Plain cached stores: lane stride is 32B,
// so the instruction pair fully covers a contiguous 2KB span per wave -> L2
// writeback merges to full lines (no RMW amplification).
__device__ __forceinline__ void putrow(f4* __restrict__ ef, size_t e, size_t er,
                                       F3 rw, F3 rm) {
    float nw = nrm3(rw), nm = nrm3(rm);
    f4 v0 = {rw.x, rw.y, rw.z, nw};
    f4 v1 = {rm.x, rm.y, rm.z, nm};
    f4 v2 = {-rw.x, -rw.y, -rw.z, nw};
    f4 v3 = {-rm.x, -rm.y, -rm.z, nm};
    ef[2 * e + 0]  = v0;
    ef[2 * e + 1]  = v1;
    ef[2 * er + 0] = v2;
    ef[2 * er + 1] = v3;
}

__global__ void __launch_bounds__(256) fused(const float* __restrict__ world,
                                             const float* __restrict__ prev,
                                             const float* __restrict__ mesh,
                                             const int* __restrict__ ntype,
                                             const int* __restrict__ cells,
                                             f4* __restrict__ nf,
                                             f4* __restrict__ ef,
                                             int n_nodes, int n_cells, int edge_blocks) {
    if ((int)blockIdx.x < edge_blocks) {
        // ---------------- edge path: 1 cell per thread ----------------
        int c = blockIdx.x * 256 + threadIdx.x;
        if (c >= n_cells) return;
        I3 t;
        __builtin_memcpy(&t, cells + 3 * (size_t)c, sizeof(I3));   // dwordx3, lane-dense

        F3 wa = ldf3(world + 3 * (size_t)t.a);
        F3 wb = ldf3(world + 3 * (size_t)t.b);
        F3 wc = ldf3(world + 3 * (size_t)t.c);
        F3 ma = ldf3(mesh + 3 * (size_t)t.a);
        F3 mb = ldf3(mesh + 3 * (size_t)t.b);
        F3 mc = ldf3(mesh + 3 * (size_t)t.c);

        size_t NC = (size_t)n_cells;
        size_t e = (size_t)c;
        putrow(ef, e,          e + 3 * NC, sub3(wa, wb), sub3(ma, mb));  // a->b ; b->a
        putrow(ef, e + NC,     e + 4 * NC, sub3(wb, wc), sub3(mb, mc));  // b->c ; c->b
        putrow(ef, e + 2 * NC, e + 5 * NC, sub3(wc, wa), sub3(mc, ma));  // c->a ; a->c
    } else {
        // ---------------- node path: 1 node per thread ----------------
        int n = (blockIdx.x - edge_blocks) * 256 + threadIdx.x;
        if (n >= n_nodes) return;
        F3 w = ldf3(world + 3 * (size_t)n);   // dwordx3, lane-dense (12B stride)
        F3 p = ldf3(prev + 3 * (size_t)n);
        int t = ntype[n];
        f4* dst = nf + 3 * (size_t)n;         // 48B per row, lane stride 48B
        f4 r0 = {w.x - p.x, w.y - p.y, w.z - p.z, t == 0 ? 1.f : 0.f};
        f4 r1 = {t == 1 ? 1.f : 0.f, t == 2 ? 1.f : 0.f, t == 3 ? 1.f : 0.f, t == 4 ? 1.f : 0.f};
        f4 r2 = {t == 5 ? 1.f : 0.f, t == 6 ? 1.f : 0.f, t == 7 ? 1.f : 0.f, t == 8 ? 1.f : 0.f};
        dst[0] = r0;
        dst[1] = r1;
        dst[2] = r2;
    }
}

extern "C" void kernel_launch(void* const* d_in, const int* in_sizes, int n_in,
                              void* d_out, int out_size, void* d_ws, size_t ws_size,
                              hipStream_t stream) {
    const float* world = (const float*)d_in[0];
    const float* prev  = (const float*)d_in[1];
    const float* mesh  = (const float*)d_in[2];
    const int* ntype   = (const int*)d_in[3];
    const int* cells   = (const int*)d_in[4];
    int n_nodes = in_sizes[0] / 3;   // 1,000,000
    int n_cells = in_sizes[4] / 3;   // 2,000,000

    float* out = (float*)d_out;
    f4* nf = (f4*)out;                                   // node features: n_nodes x 12 f32
    f4* ef = (f4*)(out + (size_t)n_nodes * 12);          // edge features: 6*n_cells x 8 f32

    int edge_blocks = (n_cells + 255) / 256;
    int node_blocks = (n_nodes + 255) / 256;

    fused<<<dim3(edge_blocks + node_blocks), dim3(256), 0, stream>>>(
        world, prev, mesh, ntype, cells, nf, ef, n_nodes, n_cells, edge_blocks);
}

// Round 5
// 532.856 us; speedup vs baseline: 1.8016x; 1.0254x over previous
//
#include <hip/hip_runtime.h>

typedef float f4 __attribute__((ext_vector_type(4)));

struct F3 { float x, y, z; };
struct F9 { float v[9]; };
struct I3 { int a, b, c; };

#define BLK 256

__device__ __forceinline__ f4 mkf4(float a, float b, float c, float d) {
    f4 v; v.x = a; v.y = b; v.z = c; v.w = d; return v;
}
__device__ __forceinline__ F3 sub3p(const float* a, const float* b) {
    F3 r; r.x = a[0] - b[0]; r.y = a[1] - b[1]; r.z = a[2] - b[2]; return r;
}
__device__ __forceinline__ float nrm3(F3 v) { return sqrtf(v.x * v.x + v.y * v.y + v.z * v.z); }

// Edge LDS: [plane 0=world/1=mesh][region 0..2][cell] of f4. Flush j -> plane j&1,
// cell j>>1: 2-way bank alias only (free per m136). Node LDS: [3][BLK+1] f4 (pad
// breaks the 3-stride alias). Both flushes are 16B-lane-stride dense -> each nt
// store instruction fully covers its 64B lines (no partial-line amplification).

__global__ void __launch_bounds__(BLK) fused(const float* __restrict__ world,
                                             const float* __restrict__ prev,
                                             const float* __restrict__ mesh,
                                             const int* __restrict__ ntype,
                                             const int* __restrict__ cells,
                                             f4* __restrict__ nf,
                                             f4* __restrict__ ef,
                                             int n_nodes, int n_cells, int edge_blocks) {
    __shared__ __align__(16) unsigned char smem[2 * 3 * BLK * 16];   // 24 KB
    int lt = threadIdx.x;

    if ((int)blockIdx.x < edge_blocks) {
        f4 (*lds)[3][BLK] = (f4 (*)[3][BLK])smem;   // [2][3][BLK]
        int c0 = blockIdx.x * BLK;
        int chunk = min(BLK, n_cells - c0);
        F3 rw[3], rm[3];
        float nw[3], nm[3];
        if (lt < chunk) {
            I3 t;
            __builtin_memcpy(&t, cells + 3 * (size_t)(c0 + lt), sizeof(I3));   // dwordx3
            F9 w9, m9;
            if (t.b == t.a + 1 && t.c == t.a + 2) {
                // cells are (base, base+1, base+2): one contiguous 36B load per array
                __builtin_memcpy(&w9, world + 3 * (size_t)t.a, sizeof(F9));
                __builtin_memcpy(&m9, mesh  + 3 * (size_t)t.a, sizeof(F9));
            } else {
                // generic (wraparound / arbitrary cells) fallback
                __builtin_memcpy(&w9.v[0], world + 3 * (size_t)t.a, 12);
                __builtin_memcpy(&w9.v[3], world + 3 * (size_t)t.b, 12);
                __builtin_memcpy(&w9.v[6], world + 3 * (size_t)t.c, 12);
                __builtin_memcpy(&m9.v[0], mesh  + 3 * (size_t)t.a, 12);
                __builtin_memcpy(&m9.v[3], mesh  + 3 * (size_t)t.b, 12);
                __builtin_memcpy(&m9.v[6], mesh  + 3 * (size_t)t.c, 12);
            }
            rw[0] = sub3p(&w9.v[0], &w9.v[3]); rm[0] = sub3p(&m9.v[0], &m9.v[3]);  // a-b
            rw[1] = sub3p(&w9.v[3], &w9.v[6]); rm[1] = sub3p(&m9.v[3], &m9.v[6]);  // b-c
            rw[2] = sub3p(&w9.v[6], &w9.v[0]); rm[2] = sub3p(&m9.v[6], &m9.v[0]);  // c-a
            #pragma unroll
            for (int r = 0; r < 3; r++) { nw[r] = nrm3(rw[r]); nm[r] = nrm3(rm[r]); }
            #pragma unroll
            for (int r = 0; r < 3; r++) {
                lds[0][r][lt] = mkf4(rw[r].x, rw[r].y, rw[r].z, nw[r]);
                lds[1][r][lt] = mkf4(rm[r].x, rm[r].y, rm[r].z, nm[r]);
            }
        }
        __syncthreads();
        size_t NC = (size_t)n_cells;
        // ---- flush forward regions 0..2 ----
        if (chunk == BLK) {
            #pragma unroll
            for (int r = 0; r < 3; r++) {
                f4* G = ef + 2 * ((size_t)r * NC + (size_t)c0);
                __builtin_nontemporal_store(lds[lt & 1][r][lt >> 1], G + lt);
                int j = lt + BLK;
                __builtin_nontemporal_store(lds[j & 1][r][j >> 1], G + j);
            }
        } else {
            for (int r = 0; r < 3; r++) {
                f4* G = ef + 2 * ((size_t)r * NC + (size_t)c0);
                for (int j = lt; j < 2 * chunk; j += BLK)
                    __builtin_nontemporal_store(lds[j & 1][r][j >> 1], G + j);
            }
        }
        __syncthreads();
        // ---- restage reversed rows (negated rels, same norms) ----
        if (lt < chunk) {
            #pragma unroll
            for (int r = 0; r < 3; r++) {
                lds[0][r][lt] = mkf4(-rw[r].x, -rw[r].y, -rw[r].z, nw[r]);
                lds[1][r][lt] = mkf4(-rm[r].x, -rm[r].y, -rm[r].z, nm[r]);
            }
        }
        __syncthreads();
        // ---- flush reverse regions 3..5 ----
        if (chunk == BLK) {
            #pragma unroll
            for (int r = 0; r < 3; r++) {
                f4* G = ef + 2 * (((size_t)r + 3) * NC + (size_t)c0);
                __builtin_nontemporal_store(lds[lt & 1][r][lt >> 1], G + lt);
                int j = lt + BLK;
                __builtin_nontemporal_store(lds[j & 1][r][j >> 1], G + j);
            }
        } else {
            for (int r = 0; r < 3; r++) {
                f4* G = ef + 2 * (((size_t)r + 3) * NC + (size_t)c0);
                for (int j = lt; j < 2 * chunk; j += BLK)
                    __builtin_nontemporal_store(lds[j & 1][r][j >> 1], G + j);
            }
        }
    } else {
        // ---------------- node path ----------------
        f4 (*lds)[BLK + 1] = (f4 (*)[BLK + 1])smem;   // [3][BLK+1]
        int n0 = (blockIdx.x - edge_blocks) * BLK;
        int chunk = min(BLK, n_nodes - n0);
        int n = n0 + lt;
        if (lt < chunk) {
            F3 w, p;
            __builtin_memcpy(&w, world + 3 * (size_t)n, sizeof(F3));
            __builtin_memcpy(&p, prev + 3 * (size_t)n, sizeof(F3));
            int t = ntype[n];
            lds[0][lt] = mkf4(w.x - p.x, w.y - p.y, w.z - p.z, t == 0 ? 1.f : 0.f);
            lds[1][lt] = mkf4(t == 1 ? 1.f : 0.f, t == 2 ? 1.f : 0.f, t == 3 ? 1.f : 0.f, t == 4 ? 1.f : 0.f);
            lds[2][lt] = mkf4(t == 5 ? 1.f : 0.f, t == 6 ? 1.f : 0.f, t == 7 ? 1.f : 0.f, t == 8 ? 1.f : 0.f);
        }
        __syncthreads();
        f4* G = nf + 3 * (size_t)n0;
        if (chunk == BLK) {
            #pragma unroll
            for (int m = 0; m < 3; m++) {
                int j = lt + m * BLK;
                __builtin_nontemporal_store(lds[j % 3][j / 3], G + j);
            }
        } else {
            for (int j = lt; j < 3 * chunk; j += BLK)
                __builtin_nontemporal_store(lds[j % 3][j / 3], G + j);
        }
    }
}

extern "C" void kernel_launch(void* const* d_in, const int* in_sizes, int n_in,
                              void* d_out, int out_size, void* d_ws, size_t ws_size,
                              hipStream_t stream) {
    const float* world = (const float*)d_in[0];
    const float* prev  = (const float*)d_in[1];
    const float* mesh  = (const float*)d_in[2];
    const int* ntype   = (const int*)d_in[3];
    const int* cells   = (const int*)d_in[4];
    int n_nodes = in_sizes[0] / 3;   // 1,000,000
    int n_cells = in_sizes[4] / 3;   // 2,000,000

    float* out = (float*)d_out;
    f4* nf = (f4*)out;                                   // node features: n_nodes x 12 f32
    f4* ef = (f4*)(out + (size_t)n_nodes * 12);          // edge features: 6*n_cells x 8 f32

    int edge_blocks = (n_cells + BLK - 1) / BLK;
    int node_blocks = (n_nodes + BLK - 1) / BLK;

    fused<<<dim3(edge_blocks + node_blocks), dim3(BLK), 0, stream>>>(
        world, prev, mesh, ntype, cells, nf, ef, n_nodes, n_cells, edge_blocks);
}

// Round 6
// 503.787 us; speedup vs baseline: 1.9056x; 1.0577x over previous
//
#include <hip/hip_runtime.h>

typedef float f4 __attribute__((ext_vector_type(4)));

struct F3 { float x, y, z; };
struct F6 { float v[6]; };
struct F9 { float v[9]; };
struct I3 { int a, b, c; };

#define BLK 256

__device__ __forceinline__ f4 mkf4(float a, float b, float c, float d) {
    f4 v; v.x = a; v.y = b; v.z = c; v.w = d; return v;
}
__device__ __forceinline__ F3 sub3p(const float* a, const float* b) {
    F3 r; r.x = a[0] - b[0]; r.y = a[1] - b[1]; r.z = a[2] - b[2]; return r;
}
__device__ __forceinline__ float nrm3(F3 v) { return sqrtf(v.x * v.x + v.y * v.y + v.z * v.z); }

// ---- Kernel A: per-node edge-row precompute (coalesced) ----
// R[n] = { world[n]-world[n+1], |.|,  mesh[n]-mesh[n+1], |.| }  (8 floats = 32B)
// Defined for n in [0, n_nodes-1). Plain cached stores: R must stay LLC-resident.
__global__ void __launch_bounds__(BLK) precompute_R(const float* __restrict__ world,
                                                    const float* __restrict__ mesh,
                                                    float* __restrict__ R, int n_nodes) {
    int n = blockIdx.x * BLK + threadIdx.x;
    if (n >= n_nodes - 1) return;
    F6 w, m;
    __builtin_memcpy(&w, world + 3 * (size_t)n, sizeof(F6));   // 24B: node n and n+1
    __builtin_memcpy(&m, mesh + 3 * (size_t)n, sizeof(F6));
    float dwx = w.v[0] - w.v[3], dwy = w.v[1] - w.v[4], dwz = w.v[2] - w.v[5];
    float dmx = m.v[0] - m.v[3], dmy = m.v[1] - m.v[4], dmz = m.v[2] - m.v[5];
    f4* Rp = (f4*)R + 2 * (size_t)n;
    Rp[0] = mkf4(dwx, dwy, dwz, sqrtf(dwx * dwx + dwy * dwy + dwz * dwz));
    Rp[1] = mkf4(dmx, dmy, dmz, sqrtf(dmx * dmx + dmy * dmy + dmz * dmz));
}

// ---- Kernel B: fused edge + node feature build ----
// Edge LDS: [plane 0=world/1=mesh][region][cell] f4; flush j -> plane j&1, cell j>>1
// (2-way bank alias only). Dense 16B-lane-stride nt stores: full 64B line coverage
// per instruction (no partial-line amplification) and no LLC allocation (protects R).
__global__ void __launch_bounds__(BLK) fused(const float* __restrict__ world,
                                             const float* __restrict__ prev,
                                             const float* __restrict__ mesh,
                                             const int* __restrict__ ntype,
                                             const int* __restrict__ cells,
                                             const float* __restrict__ R,   // may be null
                                             f4* __restrict__ nf,
                                             f4* __restrict__ ef,
                                             int n_nodes, int n_cells, int edge_blocks) {
    __shared__ __align__(16) unsigned char smem[2 * 3 * BLK * 16];   // 24 KB
    int lt = threadIdx.x;

    if ((int)blockIdx.x < edge_blocks) {
        f4 (*lds)[3][BLK] = (f4 (*)[3][BLK])smem;   // [2][3][BLK]
        int c0 = blockIdx.x * BLK;
        int chunk = min(BLK, n_cells - c0);
        F3 rw[3], rm[3];
        float nw[3], nm[3];
        if (lt < chunk) {
            I3 t;
            __builtin_memcpy(&t, cells + 3 * (size_t)(c0 + lt), sizeof(I3));   // dwordx3
            bool fast = (R != nullptr) && (t.b == t.a + 1) && (t.c == t.a + 2);
            if (fast) {
                // One 64B contiguous, 32B-aligned gather: R[a], R[a+1]
                const f4* Rp = (const f4*)R + 2 * (size_t)t.a;
                f4 w0 = Rp[0], m0 = Rp[1], w1 = Rp[2], m1 = Rp[3];
                rw[0].x = w0.x; rw[0].y = w0.y; rw[0].z = w0.z; nw[0] = w0.w;   // a->b
                rm[0].x = m0.x; rm[0].y = m0.y; rm[0].z = m0.z; nm[0] = m0.w;
                rw[1].x = w1.x; rw[1].y = w1.y; rw[1].z = w1.z; nw[1] = w1.w;   // b->c
                rm[1].x = m1.x; rm[1].y = m1.y; rm[1].z = m1.z; nm[1] = m1.w;
                float sx = w0.x + w1.x, sy = w0.y + w1.y, sz = w0.z + w1.z;     // c->a = -(d0+d1)
                rw[2].x = -sx; rw[2].y = -sy; rw[2].z = -sz;
                nw[2] = sqrtf(sx * sx + sy * sy + sz * sz);
                float ux = m0.x + m1.x, uy = m0.y + m1.y, uz = m0.z + m1.z;
                rm[2].x = -ux; rm[2].y = -uy; rm[2].z = -uz;
                nm[2] = sqrtf(ux * ux + uy * uy + uz * uz);
            } else {
                // generic path (wraparound cells / arbitrary meshes / no workspace)
                F9 w9, m9;
                __builtin_memcpy(&w9.v[0], world + 3 * (size_t)t.a, 12);
                __builtin_memcpy(&w9.v[3], world + 3 * (size_t)t.b, 12);
                __builtin_memcpy(&w9.v[6], world + 3 * (size_t)t.c, 12);
                __builtin_memcpy(&m9.v[0], mesh + 3 * (size_t)t.a, 12);
                __builtin_memcpy(&m9.v[3], mesh + 3 * (size_t)t.b, 12);
                __builtin_memcpy(&m9.v[6], mesh + 3 * (size_t)t.c, 12);
                rw[0] = sub3p(&w9.v[0], &w9.v[3]); rm[0] = sub3p(&m9.v[0], &m9.v[3]);
                rw[1] = sub3p(&w9.v[3], &w9.v[6]); rm[1] = sub3p(&m9.v[3], &m9.v[6]);
                rw[2] = sub3p(&w9.v[6], &w9.v[0]); rm[2] = sub3p(&m9.v[6], &m9.v[0]);
                #pragma unroll
                for (int r = 0; r < 3; r++) { nw[r] = nrm3(rw[r]); nm[r] = nrm3(rm[r]); }
            }
            #pragma unroll
            for (int r = 0; r < 3; r++) {
                lds[0][r][lt] = mkf4(rw[r].x, rw[r].y, rw[r].z, nw[r]);
                lds[1][r][lt] = mkf4(rm[r].x, rm[r].y, rm[r].z, nm[r]);
            }
        }
        __syncthreads();
        size_t NC = (size_t)n_cells;
        // ---- flush forward regions 0..2 ----
        if (chunk == BLK) {
            #pragma unroll
            for (int r = 0; r < 3; r++) {
                f4* G = ef + 2 * ((size_t)r * NC + (size_t)c0);
                __builtin_nontemporal_store(lds[lt & 1][r][lt >> 1], G + lt);
                int j = lt + BLK;
                __builtin_nontemporal_store(lds[j & 1][r][j >> 1], G + j);
            }
        } else {
            for (int r = 0; r < 3; r++) {
                f4* G = ef + 2 * ((size_t)r * NC + (size_t)c0);
                for (int j = lt; j < 2 * chunk; j += BLK)
                    __builtin_nontemporal_store(lds[j & 1][r][j >> 1], G + j);
            }
        }
        __syncthreads();
        // ---- restage reversed rows (negated rels, same norms) ----
        if (lt < chunk) {
            #pragma unroll
            for (int r = 0; r < 3; r++) {
                lds[0][r][lt] = mkf4(-rw[r].x, -rw[r].y, -rw[r].z, nw[r]);
                lds[1][r][lt] = mkf4(-rm[r].x, -rm[r].y, -rm[r].z, nm[r]);
            }
        }
        __syncthreads();
        // ---- flush reverse regions 3..5 ----
        if (chunk == BLK) {
            #pragma unroll
            for (int r = 0; r < 3; r++) {
                f4* G = ef + 2 * (((size_t)r + 3) * NC + (size_t)c0);
                __builtin_nontemporal_store(lds[lt & 1][r][lt >> 1], G + lt);
                int j = lt + BLK;
                __builtin_nontemporal_store(lds[j & 1][r][j >> 1], G + j);
            }
        } else {
            for (int r = 0; r < 3; r++) {
                f4* G = ef + 2 * (((size_t)r + 3) * NC + (size_t)c0);
                for (int j = lt; j < 2 * chunk; j += BLK)
                    __builtin_nontemporal_store(lds[j & 1][r][j >> 1], G + j);
            }
        }
    } else {
        // ---------------- node path ----------------
        f4 (*lds)[BLK + 1] = (f4 (*)[BLK + 1])smem;   // [3][BLK+1]
        int n0 = (blockIdx.x - edge_blocks) * BLK;
        int chunk = min(BLK, n_nodes - n0);
        int n = n0 + lt;
        if (lt < chunk) {
            F3 w, p;
            __builtin_memcpy(&w, world + 3 * (size_t)n, sizeof(F3));
            __builtin_memcpy(&p, prev + 3 * (size_t)n, sizeof(F3));
            int t = ntype[n];
            lds[0][lt] = mkf4(w.x - p.x, w.y - p.y, w.z - p.z, t == 0 ? 1.f : 0.f);
            lds[1][lt] = mkf4(t == 1 ? 1.f : 0.f, t == 2 ? 1.f : 0.f, t == 3 ? 1.f : 0.f, t == 4 ? 1.f : 0.f);
            lds[2][lt] = mkf4(t == 5 ? 1.f : 0.f, t == 6 ? 1.f : 0.f, t == 7 ? 1.f : 0.f, t == 8 ? 1.f : 0.f);
        }
        __syncthreads();
        f4* G = nf + 3 * (size_t)n0;
        if (chunk == BLK) {
            #pragma unroll
            for (int m = 0; m < 3; m++) {
                int j = lt + m * BLK;
                __builtin_nontemporal_store(lds[j % 3][j / 3], G + j);
            }
        } else {
            for (int j = lt; j < 3 * chunk; j += BLK)
                __builtin_nontemporal_store(lds[j % 3][j / 3], G + j);
        }
    }
}

extern "C" void kernel_launch(void* const* d_in, const int* in_sizes, int n_in,
                              void* d_out, int out_size, void* d_ws, size_t ws_size,
                              hipStream_t stream) {
    const float* world = (const float*)d_in[0];
    const float* prev  = (const float*)d_in[1];
    const float* mesh  = (const float*)d_in[2];
    const int* ntype   = (const int*)d_in[3];
    const int* cells   = (const int*)d_in[4];
    int n_nodes = in_sizes[0] / 3;   // 1,000,000
    int n_cells = in_sizes[4] / 3;   // 2,000,000

    float* out = (float*)d_out;
    f4* nf = (f4*)out;                                   // node features: n_nodes x 12 f32
    f4* ef = (f4*)(out + (size_t)n_nodes * 12);          // edge features: 6*n_cells x 8 f32

    const float* Rptr = nullptr;
    size_t need = (size_t)n_nodes * 32;                  // 32B per node
    if (d_ws != nullptr && ws_size >= need && n_nodes >= 2) {
        int pre_blocks = (n_nodes - 1 + BLK - 1) / BLK;
        precompute_R<<<dim3(pre_blocks), dim3(BLK), 0, stream>>>(world, mesh, (float*)d_ws, n_nodes);
        Rptr = (const float*)d_ws;
    }

    int edge_blocks = (n_cells + BLK - 1) / BLK;
    int node_blocks = (n_nodes + BLK - 1) / BLK;
    fused<<<dim3(edge_blocks + node_blocks), dim3(BLK), 0, stream>>>(
        world, prev, mesh, ntype, cells, Rptr, nf, ef, n_nodes, n_cells, edge_blocks);
}